// Round 6
// baseline (163.092 us; speedup 1.0000x reference)
//
#include <hip/hip_runtime.h>
#include <math.h>

#define D 256
#define S 512
#define M 2048  // 4 * 512
#define CH (64 * 1024)  // 256KB workspace chunk in floats
#define LTW 76  // lt row width (ushorts), padded

typedef __attribute__((ext_vector_type(8))) short bf16x8;
typedef __attribute__((ext_vector_type(4))) float f32x4;
typedef _Float16 half2v __attribute__((ext_vector_type(2)));

__device__ inline ushort f2bf(float f) {
    union { float f; unsigned u; } v; v.f = f;
    unsigned r = v.u + 0x7FFFu + ((v.u >> 16) & 1u);   // RNE
    return (ushort)(r >> 16);
}

__device__ inline ushort f2h(float f) {
    union { _Float16 h; ushort u; } v; v.h = (_Float16)f; return v.u;
}

__device__ inline uint pack2h(float a, float b) {
    union { half2v h; uint u; } v; v.h[0] = (_Float16)a; v.h[1] = (_Float16)b;
    return v.u;
}

__device__ inline uint pack2u(ushort a, ushort b) {
    return (uint)a | ((uint)b << 16);
}

// relu(a + b) on packed f16 pairs (bit patterns in uint)
__device__ inline uint addrelu2(uint a, uint b) {
    union { uint u; half2v h; } x, y;
    x.u = a; y.u = b;
    half2v s = x.h + y.h;                  // v_pk_add_f16
    half2v z = {};
    s = __builtin_elementwise_max(s, z);   // v_pk_max_f16
    union { half2v h; uint u; } r; r.h = s; return r.u;
}

// acc += dot2(a, b) — f32 accumulate (v_dot2_f32_f16)
__device__ inline float fdot2u(uint a, uint b, float acc) {
    union { uint u; half2v h; } x, y;
    x.u = a; y.u = b;
    return __builtin_amdgcn_fdot2(x.h, y.h, acc, false);
}

// ---------------------------------------------------------------------------
// Kernel A: fused weight-pack + QKV MFMA GEMM.
//   Blocks 0..383: gemm unit (bn = u%12 -> 64-col tile of {WA|WB|Wv}, bm = u/12
//   -> 64-row tile of x).  Packs its own B-tile (bf16 [col][k]) into LDS, runs
//   K-loop.  Outputs:
//     region 0 -> hi_p  [hp][row] uint: packed f16 pair {h=2hp, 2hp+1} (+b1)
//     region 1 -> hj    [row][h]  f16 row-major (coalesced via LDS stage)
//     region 2 -> vals_t [b][e][j] bf16 transposed
//   Blocks 384..399: pack Wot (Wo^T bf16) for kernel C.
// ---------------------------------------------------------------------------
__global__ __launch_bounds__(256) void qkv_pack_k(
    const float* __restrict__ x, const float* __restrict__ W1,
    const float* __restrict__ Wv, const float* __restrict__ Wo,
    const float* __restrict__ b1, const float* __restrict__ bv,
    uint* __restrict__ hi_p, ushort* __restrict__ hj,
    ushort* __restrict__ vals_t, ushort* __restrict__ Wot)
{
    __shared__ union {
        ushort Bs[64][264];   // packed B-tile [col_local][k], +8 pad
        ushort lt[64][LTW];   // transpose staging
    } sh;

    const int u = blockIdx.x;
    const int t = threadIdx.x;

    if (u >= 384) {
        // ---- Wot pack unit (16 blocks): Wot[n][k] = bf16(Wo[k][n]) ----
        const int unit = u - 384;
        const int a0 = (unit >> 2) * 64;   // dst row block (n = src col)
        const int b0 = (unit & 3) * 64;    // dst col block (k = src row)
        const int r = t >> 4;
        const int c = (t & 15) * 4;
#pragma unroll
        for (int p = 0; p < 4; ++p) {
            const int sr = b0 + p * 16 + r;
            float4 v = *(const float4*)(Wo + (size_t)sr * 256 + a0 + c);
            sh.lt[p * 16 + r][c + 0] = f2bf(v.x);
            sh.lt[p * 16 + r][c + 1] = f2bf(v.y);
            sh.lt[p * 16 + r][c + 2] = f2bf(v.z);
            sh.lt[p * 16 + r][c + 3] = f2bf(v.w);
        }
        __syncthreads();
#pragma unroll
        for (int p = 0; p < 4; ++p) {
            const int dr = p * 16 + r;
            ushort4 o = make_ushort4(sh.lt[c + 0][dr], sh.lt[c + 1][dr],
                                     sh.lt[c + 2][dr], sh.lt[c + 3][dr]);
            *(ushort4*)(Wot + (size_t)(a0 + dr) * 256 + b0 + c) = o;
        }
        return;
    }

    // ---- QKV gemm unit ----
    const int bn = u % 12, bm = u / 12;
    const int n0 = bn * 64, m0 = bm * 64;
    const int region = n0 >> 8, c0 = n0 & 255;

    // pack B-tile into LDS: Bs[cl][k] = bf16(Wsrc[k][c0+cl])
    {
        const int cl4 = (t & 15) * 4;
        const int kb = (t >> 4) * 16;
#pragma unroll
        for (int kk = 0; kk < 16; ++kk) {
            const int k = kb + kk;
            float4 v;
            if (region == 0) {
                float4 wa = *(const float4*)(W1 + (size_t)k * 256 + c0 + cl4);
                float4 wc = *(const float4*)(W1 + (size_t)(512 + k) * 256 + c0 + cl4);
                v = make_float4(wa.x + wc.x, wa.y + wc.y, wa.z + wc.z, wa.w + wc.w);
            } else if (region == 1) {
                float4 wb = *(const float4*)(W1 + (size_t)(256 + k) * 256 + c0 + cl4);
                float4 wc = *(const float4*)(W1 + (size_t)(512 + k) * 256 + c0 + cl4);
                v = make_float4(wb.x - wc.x, wb.y - wc.y, wb.z - wc.z, wb.w - wc.w);
            } else {
                v = *(const float4*)(Wv + (size_t)k * 256 + c0 + cl4);
            }
            sh.Bs[cl4 + 0][k] = f2bf(v.x);
            sh.Bs[cl4 + 1][k] = f2bf(v.y);
            sh.Bs[cl4 + 2][k] = f2bf(v.z);
            sh.Bs[cl4 + 3][k] = f2bf(v.w);
        }
    }
    __syncthreads();

    const int w = t >> 6, l = t & 63;
    const int q = l >> 4, ln = l & 15;
    const int wm = (w >> 1) * 32, wn = (w & 1) * 32;

    f32x4 acc[2][2] = {};
    for (int k0 = 0; k0 < 256; k0 += 32) {
        union { bf16x8 v; ushort s[8]; } a[2];
        bf16x8 b[2];
#pragma unroll
        for (int mt = 0; mt < 2; ++mt) {
            const float* xr = x + (size_t)(m0 + wm + mt * 16 + ln) * 256 + k0 + q * 8;
            float4 u0 = *(const float4*)xr;
            float4 u1 = *(const float4*)(xr + 4);
            a[mt].s[0] = f2bf(u0.x); a[mt].s[1] = f2bf(u0.y);
            a[mt].s[2] = f2bf(u0.z); a[mt].s[3] = f2bf(u0.w);
            a[mt].s[4] = f2bf(u1.x); a[mt].s[5] = f2bf(u1.y);
            a[mt].s[6] = f2bf(u1.z); a[mt].s[7] = f2bf(u1.w);
        }
#pragma unroll
        for (int nt = 0; nt < 2; ++nt)
            b[nt] = *(const bf16x8*)&sh.Bs[wn + nt * 16 + ln][k0 + q * 8];
#pragma unroll
        for (int mt = 0; mt < 2; ++mt)
#pragma unroll
            for (int nt = 0; nt < 2; ++nt)
                acc[mt][nt] = __builtin_amdgcn_mfma_f32_16x16x32_bf16(a[mt].v, b[nt], acc[mt][nt], 0, 0, 0);
    }

    __syncthreads();   // all Bs reads done before aliasing as lt

    if (region == 0) {
        // stage f16(acc + b1) into lt[col_local][row_local]
#pragma unroll
        for (int nt = 0; nt < 2; ++nt) {
            const int cl = wn + nt * 16 + ln;
            const float bias = b1[c0 + cl];
#pragma unroll
            for (int mt = 0; mt < 2; ++mt)
#pragma unroll
                for (int r = 0; r < 4; ++r)
                    sh.lt[cl][wm + mt * 16 + q * 4 + r] = f2h(acc[mt][nt][r] + bias);
        }
        __syncthreads();
        // readout: hi_p[(c0>>1)+hpl][m0+r4 .. +3], pair-packed, 16B coalesced
#pragma unroll
        for (int p = 0; p < 2; ++p) {
            const int qid = p * 256 + t;
            const int r4 = (qid & 15) * 4;
            const int hpl = qid >> 4;          // 0..31
            uint4 o;
            o.x = pack2u(sh.lt[2 * hpl][r4 + 0], sh.lt[2 * hpl + 1][r4 + 0]);
            o.y = pack2u(sh.lt[2 * hpl][r4 + 1], sh.lt[2 * hpl + 1][r4 + 1]);
            o.z = pack2u(sh.lt[2 * hpl][r4 + 2], sh.lt[2 * hpl + 1][r4 + 2]);
            o.w = pack2u(sh.lt[2 * hpl][r4 + 3], sh.lt[2 * hpl + 1][r4 + 3]);
            *(uint4*)(hi_p + (size_t)((c0 >> 1) + hpl) * 2048 + m0 + r4) = o;
        }
    } else if (region == 1) {
        // stage f16(acc) into lt[col_local][row_local]
#pragma unroll
        for (int nt = 0; nt < 2; ++nt) {
            const int cl = wn + nt * 16 + ln;
#pragma unroll
            for (int mt = 0; mt < 2; ++mt)
#pragma unroll
                for (int r = 0; r < 4; ++r)
                    sh.lt[cl][wm + mt * 16 + q * 4 + r] = f2h(acc[mt][nt][r]);
        }
        __syncthreads();
        // readout row-major: hj[m0+rl][c0+cg*8 ..], 16B coalesced
#pragma unroll
        for (int p = 0; p < 2; ++p) {
            const int qid = p * 256 + t;
            const int cg = qid & 7;
            const int rl = qid >> 3;           // 0..63
            ushort o[8];
#pragma unroll
            for (int k = 0; k < 8; ++k) o[k] = sh.lt[cg * 8 + k][rl];
            *(uint4*)(hj + (size_t)(m0 + rl) * 256 + c0 + cg * 8) = *(const uint4*)o;
        }
    } else {
        // stage bias-added bf16 into lt[col_local][row_local], store transposed
#pragma unroll
        for (int nt = 0; nt < 2; ++nt) {
            const int cl = wn + nt * 16 + ln;
            const float bias = bv[c0 + cl];
#pragma unroll
            for (int mt = 0; mt < 2; ++mt)
#pragma unroll
                for (int r = 0; r < 4; ++r)
                    sh.lt[cl][wm + mt * 16 + q * 4 + r] = f2bf(acc[mt][nt][r] + bias);
        }
        __syncthreads();
        const int bb = m0 >> 9, jloc = m0 & 511;
#pragma unroll
        for (int p = 0; p < 2; ++p) {
            const int idx = p * 256 + t;
            const int e_l = idx & 63, jc = (idx >> 6) * 8;
            *(uint4*)(vals_t + ((size_t)(bb * 256 + c0 + e_l)) * 512 + jloc + jc) =
                *(const uint4*)&sh.lt[e_l][jc];
        }
    }
}

// ---------------------------------------------------------------------------
// Kernel B: scores, 64i x 32j tiles, packed-f16 dot2 inner loop.
//   hi_p is pre-transposed/pair-packed by A -> NO LDS transpose, NO syncs in
//   the main loop.  hj read per-thread (row-major).
// ---------------------------------------------------------------------------
__global__ __launch_bounds__(256) void scores_k(
    const uint* __restrict__ hi_p, const ushort* __restrict__ hj,
    const float* __restrict__ w2, float* __restrict__ sc)
{
    const int jt = blockIdx.x, it = blockIdx.y, bb = blockIdx.z;
    if (jt > 2 * it + 1) return;
    const int i0 = it * 64, j0 = jt * 32;
    const int t = threadIdx.x, w = t >> 6, l = t & 63;
    const int q = l >> 4, ln = l & 15;

    __shared__ __align__(16) float Sst[64][36];    // output staging
    __shared__ uint w2u[128];                      // w2 packed half2
    if (t < 64) {
        float4 wv = *(const float4*)(w2 + t * 4);
        w2u[t * 2 + 0] = pack2h(wv.x, wv.y);
        w2u[t * 2 + 1] = pack2h(wv.z, wv.w);
    }
    __syncthreads();

    const size_t gi = (size_t)((bb << 9) + i0 + ln * 4);  // row base for a-frags
    const int jrow = w * 8 + q * 2;
    const ushort* hj0 = hj + (size_t)((bb << 9) + j0 + jrow) * 256;
    const ushort* hj1 = hj0 + 256;

    float acc00 = 0.f, acc01 = 0.f, acc10 = 0.f, acc11 = 0.f;
    float acc20 = 0.f, acc21 = 0.f, acc30 = 0.f, acc31 = 0.f;

    for (int hc = 0; hc < 256; hc += 32) {
        const int hp0 = hc >> 1;
        uint e0u[16], e1u[16];
#pragma unroll
        for (int c = 0; c < 4; ++c) {
            *(uint4*)&e0u[c * 4] = *(const uint4*)(hj0 + hc + c * 8);
            *(uint4*)&e1u[c * 4] = *(const uint4*)(hj1 + hc + c * 8);
        }
#pragma unroll
        for (int hp = 0; hp < 16; ++hp) {
            uint4 av = *(const uint4*)(hi_p + (size_t)(hp0 + hp) * 2048 + gi);
            const uint wv = w2u[hp0 + hp];
            const uint f0 = e0u[hp], f1 = e1u[hp];
            acc00 = fdot2u(addrelu2(av.x, f0), wv, acc00);
            acc01 = fdot2u(addrelu2(av.x, f1), wv, acc01);
            acc10 = fdot2u(addrelu2(av.y, f0), wv, acc10);
            acc11 = fdot2u(addrelu2(av.y, f1), wv, acc11);
            acc20 = fdot2u(addrelu2(av.z, f0), wv, acc20);
            acc21 = fdot2u(addrelu2(av.z, f1), wv, acc21);
            acc30 = fdot2u(addrelu2(av.w, f0), wv, acc30);
            acc31 = fdot2u(addrelu2(av.w, f1), wv, acc31);
        }
    }

    Sst[ln * 4 + 0][jrow] = acc00;  Sst[ln * 4 + 0][jrow + 1] = acc01;
    Sst[ln * 4 + 1][jrow] = acc10;  Sst[ln * 4 + 1][jrow + 1] = acc11;
    Sst[ln * 4 + 2][jrow] = acc20;  Sst[ln * 4 + 2][jrow + 1] = acc21;
    Sst[ln * 4 + 3][jrow] = acc30;  Sst[ln * 4 + 3][jrow + 1] = acc31;
    __syncthreads();
    const int i_l = t >> 2, jc = (t & 3) * 8;
    float* dst = sc + ((size_t)bb << 18) + (size_t)(i0 + i_l) * 512 + j0 + jc;
    *(float4*)dst       = *(const float4*)&Sst[i_l][jc];
    *(float4*)(dst + 4) = *(const float4*)&Sst[i_l][jc + 4];
}

// ---------------------------------------------------------------------------
// Kernel C: fused softmax + PV + out-proj + residual + LayerNorm.
//   512 blocks x 256 threads; block u: b = u>>7, 4-row tile m0 = (u&127)*4.
//   2 blocks/CU for overlap; MFMA M=16 runs with rows 4..15 zeroed.
// ---------------------------------------------------------------------------
__global__ __launch_bounds__(256) void smpvout_k(
    const float* __restrict__ sc, const ushort* __restrict__ vals_t,
    const ushort* __restrict__ Wot, const float* __restrict__ x,
    const float* __restrict__ bo, const float* __restrict__ gamma,
    const float* __restrict__ beta, float* __restrict__ out)
{
    const int u = blockIdx.x;
    const int b = u >> 7, m0 = (u & 127) * 4;
    const int t = threadIdx.x, w = t >> 6, l = t & 63;
    const int q = l >> 4, ln = l & 15;

    __shared__ __align__(16) ushort attnS[16][520];   // +8 pad
    __shared__ __align__(16) ushort msgS[16][264];    // +8 pad
    __shared__ float redS[4][4], redQ[4][4];

    // zero attnS rows 4..15 (4 waves x 3 rows each, 8 ushorts/lane)
#pragma unroll
    for (int p = 0; p < 3; ++p)
        *(uint4*)&attnS[4 + w + p * 4][l * 8] = make_uint4(0, 0, 0, 0);

    // ---- softmax: 4 rows, one per wave ----
    {
        const int i = m0 + w;
        const float* srow = sc + ((size_t)b << 18) + (size_t)i * S;
        const int j0 = l * 8;
        float v[8];
        *(float4*)&v[0] = *(const float4*)(srow + j0);
        *(float4*)&v[4] = *(const float4*)(srow + j0 + 4);
        float mx = -3.0e38f;
#pragma unroll
        for (int k = 0; k < 8; ++k) {
            v[k] = (j0 + k < i) ? v[k] : -3.0e38f;  // mask before ANY use
            mx = fmaxf(mx, v[k]);
        }
#pragma unroll
        for (int off = 32; off; off >>= 1) mx = fmaxf(mx, __shfl_xor(mx, off, 64));
        float e[8];
        float sum = 0.f;
#pragma unroll
        for (int k = 0; k < 8; ++k) {
            e[k] = __expf(v[k] - mx);
            sum += (j0 + k < i) ? e[k] : 0.f;
        }
#pragma unroll
        for (int off = 32; off; off >>= 1) sum += __shfl_xor(sum, off, 64);
        const float inv = (i > 0) ? (1.f / sum) : 0.f;   // row 0: all-zero
        ushort o[8];
#pragma unroll
        for (int k = 0; k < 8; ++k)
            o[k] = (j0 + k < i) ? f2bf(e[k] * inv) : (ushort)0;
        *(ushort4*)&attnS[w][j0]     = make_ushort4(o[0], o[1], o[2], o[3]);
        *(ushort4*)&attnS[w][j0 + 4] = make_ushort4(o[4], o[5], o[6], o[7]);
    }
    __syncthreads();

    // ---- PV: wave w -> cols w*64 .. w*64+63 (nt 0..3) ----
    const ushort* V = vals_t + (size_t)b * 256 * 512;
    f32x4 acc[4] = {};
    const int kmax = (m0 + 4 + 31) & ~31;   // covers j <= m0+2
    for (int k0 = 0; k0 < kmax; k0 += 32) {
        bf16x8 a = *(const bf16x8*)&attnS[ln][k0 + q * 8];
#pragma unroll
        for (int nt = 0; nt < 4; ++nt) {
            bf16x8 bb = *(const bf16x8*)(V + (size_t)(w * 64 + nt * 16 + ln) * 512 + k0 + q * 8);
            acc[nt] = __builtin_amdgcn_mfma_f32_16x16x32_bf16(a, bb, acc[nt], 0, 0, 0);
        }
    }
#pragma unroll
    for (int nt = 0; nt < 4; ++nt)
#pragma unroll
        for (int r = 0; r < 4; ++r)
            msgS[q * 4 + r][w * 64 + nt * 16 + ln] = f2bf(acc[nt][r]);
    __syncthreads();

    // ---- OUT: wave w -> cols w*64 .. w*64+63; rows 0..3 valid ----
    f32x4 acc2[4] = {};
    for (int k0 = 0; k0 < 256; k0 += 32) {
        bf16x8 a = *(const bf16x8*)&msgS[ln][k0 + q * 8];
#pragma unroll
        for (int nt = 0; nt < 4; ++nt) {
            bf16x8 bb = *(const bf16x8*)(Wot + (size_t)(w * 64 + nt * 16 + ln) * 256 + k0 + q * 8);
            acc2[nt] = __builtin_amdgcn_mfma_f32_16x16x32_bf16(a, bb, acc2[nt], 0, 0, 0);
        }
    }

    const int r0 = (b << 9) + m0;
    float sum[4] = {}, sq[4] = {};
    if (q == 0) {
#pragma unroll
        for (int nt = 0; nt < 4; ++nt) {
            const int col = w * 64 + nt * 16 + ln;
            const float bov = bo[col];
#pragma unroll
            for (int r = 0; r < 4; ++r) {
                const int row = r0 + r;
                float v = acc2[nt][r] + x[(size_t)row * 256 + col] + bov;
                acc2[nt][r] = v;
                sum[r] += v;
                sq[r] += v * v;
            }
        }
    }
#pragma unroll
    for (int r = 0; r < 4; ++r) {
#pragma unroll
        for (int off = 1; off < 16; off <<= 1) {
            sum[r] += __shfl_xor(sum[r], off, 64);
            sq[r]  += __shfl_xor(sq[r],  off, 64);
        }
    }
    if (ln == 0 && q == 0) {
#pragma unroll
        for (int r = 0; r < 4; ++r) {
            redS[r][w] = sum[r];
            redQ[r][w] = sq[r];
        }
    }
    __syncthreads();
    if (q == 0) {
#pragma unroll
        for (int nt = 0; nt < 4; ++nt) {
            const int col = w * 64 + nt * 16 + ln;
            const float g = gamma[col], be = beta[col];
#pragma unroll
            for (int r = 0; r < 4; ++r) {
                const float ts = redS[r][0] + redS[r][1] + redS[r][2] + redS[r][3];
                const float tq = redQ[r][0] + redQ[r][1] + redQ[r][2] + redQ[r][3];
                const float mu = ts * (1.f / 256.f);
                const float var = tq * (1.f / 256.f) - mu * mu;
                out[(size_t)(r0 + r) * 256 + col] =
                    (acc2[nt][r] - mu) * rsqrtf(var + 1e-5f) * g + be;
            }
        }
    }
}

// ---------------------------------------------------------------------------
extern "C" void kernel_launch(void* const* d_in, const int* in_sizes, int n_in,
                              void* d_out, int out_size, void* d_ws, size_t ws_size,
                              hipStream_t stream)
{
    (void)in_sizes; (void)n_in; (void)out_size; (void)ws_size;
    const float* x     = (const float*)d_in[0];
    const float* W1    = (const float*)d_in[1];
    const float* b1    = (const float*)d_in[2];
    const float* w2    = (const float*)d_in[3];
    const float* Wv    = (const float*)d_in[5];
    const float* bv    = (const float*)d_in[6];
    const float* Wo    = (const float*)d_in[7];
    const float* bo    = (const float*)d_in[8];
    const float* gamma = (const float*)d_in[9];
    const float* beta  = (const float*)d_in[10];
    float* out = (float*)d_out;

    // workspace layout in 256KB (64K-float) chunks
    float* ws = (float*)d_ws;
    uint*   hi_p   = (uint*)ws;                        // chunks 0-3   [128 hp][2048] uint
    ushort* hj     = (ushort*)(ws + 4 * (size_t)CH);   // chunks 4-7   [2048][256] f16
    float*  sc     = ws + 8 * (size_t)CH;              // chunks 8-23  (4*512*512 f32)
    ushort* Wot    = (ushort*)(ws + 24 * (size_t)CH);  // chunk 24
    ushort* vals_t = (ushort*)(ws + 25 * (size_t)CH);  // chunks 25-28 ([b][e][j] bf16)

    qkv_pack_k<<<dim3(400),      256, 0, stream>>>(x, W1, Wv, Wo, b1, bv, hi_p, hj, vals_t, Wot);
    scores_k  <<<dim3(16, 8, 4), 256, 0, stream>>>(hi_p, hj, w2, sc);
    smpvout_k <<<dim3(512),      256, 0, stream>>>(sc, vals_t, Wot, x, bo, gamma, beta, out);
}

// Round 7
// 134.720 us; speedup vs baseline: 1.2106x; 1.2106x over previous
//
#include <hip/hip_runtime.h>
#include <math.h>

#define D 256
#define S 512
#define M 2048  // 4 * 512
#define CH (64 * 1024)  // 256KB workspace chunk in floats
#define LTW 76  // lt row width (ushorts), padded

typedef __attribute__((ext_vector_type(8))) short bf16x8;
typedef __attribute__((ext_vector_type(4))) float f32x4;
typedef _Float16 half2v __attribute__((ext_vector_type(2)));

__device__ inline ushort f2bf(float f) {
    union { float f; unsigned u; } v; v.f = f;
    unsigned r = v.u + 0x7FFFu + ((v.u >> 16) & 1u);   // RNE
    return (ushort)(r >> 16);
}

__device__ inline ushort f2h(float f) {
    union { _Float16 h; ushort u; } v; v.h = (_Float16)f; return v.u;
}

__device__ inline uint pack2h(float a, float b) {
    union { half2v h; uint u; } v; v.h[0] = (_Float16)a; v.h[1] = (_Float16)b;
    return v.u;
}

__device__ inline uint pack2u(ushort a, ushort b) {
    return (uint)a | ((uint)b << 16);
}

// relu(a + b) on packed f16 pairs (bit patterns in uint)
__device__ inline uint addrelu2(uint a, uint b) {
    union { uint u; half2v h; } x, y;
    x.u = a; y.u = b;
    half2v s = x.h + y.h;                  // v_pk_add_f16
    half2v z = {};
    s = __builtin_elementwise_max(s, z);   // v_pk_max_f16
    union { half2v h; uint u; } r; r.h = s; return r.u;
}

// acc += dot2(a, b) — f32 accumulate (v_dot2_f32_f16)
__device__ inline float fdot2u(uint a, uint b, float acc) {
    union { uint u; half2v h; } x, y;
    x.u = a; y.u = b;
    return __builtin_amdgcn_fdot2(x.h, y.h, acc, false);
}

// ---------------------------------------------------------------------------
// Kernel A: fused weight-pack + QKV MFMA GEMM.
//   Blocks 0..383: gemm unit (bn = u%12 -> 64-col tile of {WA|WB|Wv}, bm = u/12
//   -> 64-row tile of x).  Packs its own B-tile (bf16 [col][k]) into LDS, runs
//   K-loop.  Outputs:
//     region 0 -> hi_p  [hp][row] uint: packed f16 pair {h=2hp, 2hp+1} (+b1)
//     region 1 -> hj    [row][h]  f16 row-major (coalesced via LDS stage)
//     region 2 -> vals_t [b][e][j] bf16 transposed
//   Blocks 384..399: pack Wot (Wo^T bf16) for kernel C.
// ---------------------------------------------------------------------------
__global__ __launch_bounds__(256) void qkv_pack_k(
    const float* __restrict__ x, const float* __restrict__ W1,
    const float* __restrict__ Wv, const float* __restrict__ Wo,
    const float* __restrict__ b1, const float* __restrict__ bv,
    uint* __restrict__ hi_p, ushort* __restrict__ hj,
    ushort* __restrict__ vals_t, ushort* __restrict__ Wot)
{
    __shared__ union {
        ushort Bs[64][264];   // packed B-tile [col_local][k], +8 pad
        ushort lt[64][LTW];   // transpose staging
    } sh;

    const int u = blockIdx.x;
    const int t = threadIdx.x;

    if (u >= 384) {
        // ---- Wot pack unit (16 blocks): Wot[n][k] = bf16(Wo[k][n]) ----
        const int unit = u - 384;
        const int a0 = (unit >> 2) * 64;   // dst row block (n = src col)
        const int b0 = (unit & 3) * 64;    // dst col block (k = src row)
        const int r = t >> 4;
        const int c = (t & 15) * 4;
#pragma unroll
        for (int p = 0; p < 4; ++p) {
            const int sr = b0 + p * 16 + r;
            float4 v = *(const float4*)(Wo + (size_t)sr * 256 + a0 + c);
            sh.lt[p * 16 + r][c + 0] = f2bf(v.x);
            sh.lt[p * 16 + r][c + 1] = f2bf(v.y);
            sh.lt[p * 16 + r][c + 2] = f2bf(v.z);
            sh.lt[p * 16 + r][c + 3] = f2bf(v.w);
        }
        __syncthreads();
#pragma unroll
        for (int p = 0; p < 4; ++p) {
            const int dr = p * 16 + r;
            ushort4 o = make_ushort4(sh.lt[c + 0][dr], sh.lt[c + 1][dr],
                                     sh.lt[c + 2][dr], sh.lt[c + 3][dr]);
            *(ushort4*)(Wot + (size_t)(a0 + dr) * 256 + b0 + c) = o;
        }
        return;
    }

    // ---- QKV gemm unit ----
    const int bn = u % 12, bm = u / 12;
    const int n0 = bn * 64, m0 = bm * 64;
    const int region = n0 >> 8, c0 = n0 & 255;

    // pack B-tile into LDS: Bs[cl][k] = bf16(Wsrc[k][c0+cl])
    {
        const int cl4 = (t & 15) * 4;
        const int kb = (t >> 4) * 16;
#pragma unroll
        for (int kk = 0; kk < 16; ++kk) {
            const int k = kb + kk;
            float4 v;
            if (region == 0) {
                float4 wa = *(const float4*)(W1 + (size_t)k * 256 + c0 + cl4);
                float4 wc = *(const float4*)(W1 + (size_t)(512 + k) * 256 + c0 + cl4);
                v = make_float4(wa.x + wc.x, wa.y + wc.y, wa.z + wc.z, wa.w + wc.w);
            } else if (region == 1) {
                float4 wb = *(const float4*)(W1 + (size_t)(256 + k) * 256 + c0 + cl4);
                float4 wc = *(const float4*)(W1 + (size_t)(512 + k) * 256 + c0 + cl4);
                v = make_float4(wb.x - wc.x, wb.y - wc.y, wb.z - wc.z, wb.w - wc.w);
            } else {
                v = *(const float4*)(Wv + (size_t)k * 256 + c0 + cl4);
            }
            sh.Bs[cl4 + 0][k] = f2bf(v.x);
            sh.Bs[cl4 + 1][k] = f2bf(v.y);
            sh.Bs[cl4 + 2][k] = f2bf(v.z);
            sh.Bs[cl4 + 3][k] = f2bf(v.w);
        }
    }
    __syncthreads();

    const int w = t >> 6, l = t & 63;
    const int q = l >> 4, ln = l & 15;
    const int wm = (w >> 1) * 32, wn = (w & 1) * 32;

    f32x4 acc[2][2] = {};
    for (int k0 = 0; k0 < 256; k0 += 32) {
        union { bf16x8 v; ushort s[8]; } a[2];
        bf16x8 b[2];
#pragma unroll
        for (int mt = 0; mt < 2; ++mt) {
            const float* xr = x + (size_t)(m0 + wm + mt * 16 + ln) * 256 + k0 + q * 8;
            float4 u0 = *(const float4*)xr;
            float4 u1 = *(const float4*)(xr + 4);
            a[mt].s[0] = f2bf(u0.x); a[mt].s[1] = f2bf(u0.y);
            a[mt].s[2] = f2bf(u0.z); a[mt].s[3] = f2bf(u0.w);
            a[mt].s[4] = f2bf(u1.x); a[mt].s[5] = f2bf(u1.y);
            a[mt].s[6] = f2bf(u1.z); a[mt].s[7] = f2bf(u1.w);
        }
#pragma unroll
        for (int nt = 0; nt < 2; ++nt)
            b[nt] = *(const bf16x8*)&sh.Bs[wn + nt * 16 + ln][k0 + q * 8];
#pragma unroll
        for (int mt = 0; mt < 2; ++mt)
#pragma unroll
            for (int nt = 0; nt < 2; ++nt)
                acc[mt][nt] = __builtin_amdgcn_mfma_f32_16x16x32_bf16(a[mt].v, b[nt], acc[mt][nt], 0, 0, 0);
    }

    __syncthreads();   // all Bs reads done before aliasing as lt

    if (region == 0) {
        // stage f16(acc + b1) into lt[col_local][row_local]
#pragma unroll
        for (int nt = 0; nt < 2; ++nt) {
            const int cl = wn + nt * 16 + ln;
            const float bias = b1[c0 + cl];
#pragma unroll
            for (int mt = 0; mt < 2; ++mt)
#pragma unroll
                for (int r = 0; r < 4; ++r)
                    sh.lt[cl][wm + mt * 16 + q * 4 + r] = f2h(acc[mt][nt][r] + bias);
        }
        __syncthreads();
        // readout: hi_p[(c0>>1)+hpl][m0+r4 .. +3], pair-packed, 16B coalesced
#pragma unroll
        for (int p = 0; p < 2; ++p) {
            const int qid = p * 256 + t;
            const int r4 = (qid & 15) * 4;
            const int hpl = qid >> 4;          // 0..31
            uint4 o;
            o.x = pack2u(sh.lt[2 * hpl][r4 + 0], sh.lt[2 * hpl + 1][r4 + 0]);
            o.y = pack2u(sh.lt[2 * hpl][r4 + 1], sh.lt[2 * hpl + 1][r4 + 1]);
            o.z = pack2u(sh.lt[2 * hpl][r4 + 2], sh.lt[2 * hpl + 1][r4 + 2]);
            o.w = pack2u(sh.lt[2 * hpl][r4 + 3], sh.lt[2 * hpl + 1][r4 + 3]);
            *(uint4*)(hi_p + (size_t)((c0 >> 1) + hpl) * 2048 + m0 + r4) = o;
        }
    } else if (region == 1) {
        // stage f16(acc) into lt[col_local][row_local]
#pragma unroll
        for (int nt = 0; nt < 2; ++nt) {
            const int cl = wn + nt * 16 + ln;
#pragma unroll
            for (int mt = 0; mt < 2; ++mt)
#pragma unroll
                for (int r = 0; r < 4; ++r)
                    sh.lt[cl][wm + mt * 16 + q * 4 + r] = f2h(acc[mt][nt][r]);
        }
        __syncthreads();
        // readout row-major: hj[m0+rl][c0+cg*8 ..], 16B coalesced
#pragma unroll
        for (int p = 0; p < 2; ++p) {
            const int qid = p * 256 + t;
            const int cg = qid & 7;
            const int rl = qid >> 3;           // 0..63
            ushort o[8];
#pragma unroll
            for (int k = 0; k < 8; ++k) o[k] = sh.lt[cg * 8 + k][rl];
            *(uint4*)(hj + (size_t)(m0 + rl) * 256 + c0 + cg * 8) = *(const uint4*)o;
        }
    } else {
        // stage bias-added bf16 into lt[col_local][row_local], store transposed
#pragma unroll
        for (int nt = 0; nt < 2; ++nt) {
            const int cl = wn + nt * 16 + ln;
            const float bias = bv[c0 + cl];
#pragma unroll
            for (int mt = 0; mt < 2; ++mt)
#pragma unroll
                for (int r = 0; r < 4; ++r)
                    sh.lt[cl][wm + mt * 16 + q * 4 + r] = f2bf(acc[mt][nt][r] + bias);
        }
        __syncthreads();
        const int bb = m0 >> 9, jloc = m0 & 511;
#pragma unroll
        for (int p = 0; p < 2; ++p) {
            const int idx = p * 256 + t;
            const int e_l = idx & 63, jc = (idx >> 6) * 8;
            *(uint4*)(vals_t + ((size_t)(bb * 256 + c0 + e_l)) * 512 + jloc + jc) =
                *(const uint4*)&sh.lt[e_l][jc];
        }
    }
}

// ---------------------------------------------------------------------------
// Kernel B: scores, 64i x 32j tiles, packed-f16 dot2 inner loop.
//   Full hi_p block-tile (128 hp x 64 i = 32KB) staged to LDS upfront with
//   coalesced uint4 copies + ONE sync; main loop is LDS reads + hj L2 loads
//   + dot2 VALU with ZERO barriers (freely software-pipelined).
// ---------------------------------------------------------------------------
__global__ __launch_bounds__(256) void scores_k(
    const uint* __restrict__ hi_p, const ushort* __restrict__ hj,
    const float* __restrict__ w2, float* __restrict__ sc)
{
    const int jt = blockIdx.x, it = blockIdx.y, bb = blockIdx.z;
    if (jt > 2 * it + 1) return;
    const int i0 = it * 64, j0 = jt * 32;
    const int t = threadIdx.x, w = t >> 6, l = t & 63;
    const int q = l >> 4, ln = l & 15;

    __shared__ __align__(16) uint Hi[128][64];     // [hp][i_local] packed half2
    __shared__ __align__(16) float Sst[64][36];    // output staging
    __shared__ uint w2u[128];                      // w2 packed half2

    if (t < 64) {
        float4 wv = *(const float4*)(w2 + t * 4);
        w2u[t * 2 + 0] = pack2h(wv.x, wv.y);
        w2u[t * 2 + 1] = pack2h(wv.z, wv.w);
    }
    // stage hi_p tile: 128 hp x 64 i, 8 uint4 per thread, coalesced
    {
        const int gbase = (bb << 9) + i0;
#pragma unroll
        for (int p = 0; p < 8; ++p) {
            const int idx = p * 256 + t;
            const int hp = idx >> 4;
            const int il = (idx & 15) * 4;
            *(uint4*)&Hi[hp][il] =
                *(const uint4*)(hi_p + (size_t)hp * 2048 + gbase + il);
        }
    }
    __syncthreads();

    const int jrow = w * 8 + q * 2;
    const ushort* hj0 = hj + (size_t)((bb << 9) + j0 + jrow) * 256;
    const ushort* hj1 = hj0 + 256;
    const int i4 = ln * 4;

    float acc00 = 0.f, acc01 = 0.f, acc10 = 0.f, acc11 = 0.f;
    float acc20 = 0.f, acc21 = 0.f, acc30 = 0.f, acc31 = 0.f;

    for (int hc = 0; hc < 256; hc += 32) {
        const int hp0 = hc >> 1;
        uint e0u[16], e1u[16];
#pragma unroll
        for (int c = 0; c < 4; ++c) {
            *(uint4*)&e0u[c * 4] = *(const uint4*)(hj0 + hc + c * 8);
            *(uint4*)&e1u[c * 4] = *(const uint4*)(hj1 + hc + c * 8);
        }
#pragma unroll
        for (int hp = 0; hp < 16; ++hp) {
            uint4 av = *(const uint4*)&Hi[hp0 + hp][i4];
            const uint wv = w2u[hp0 + hp];
            const uint f0 = e0u[hp], f1 = e1u[hp];
            acc00 = fdot2u(addrelu2(av.x, f0), wv, acc00);
            acc01 = fdot2u(addrelu2(av.x, f1), wv, acc01);
            acc10 = fdot2u(addrelu2(av.y, f0), wv, acc10);
            acc11 = fdot2u(addrelu2(av.y, f1), wv, acc11);
            acc20 = fdot2u(addrelu2(av.z, f0), wv, acc20);
            acc21 = fdot2u(addrelu2(av.z, f1), wv, acc21);
            acc30 = fdot2u(addrelu2(av.w, f0), wv, acc30);
            acc31 = fdot2u(addrelu2(av.w, f1), wv, acc31);
        }
    }

    Sst[ln * 4 + 0][jrow] = acc00;  Sst[ln * 4 + 0][jrow + 1] = acc01;
    Sst[ln * 4 + 1][jrow] = acc10;  Sst[ln * 4 + 1][jrow + 1] = acc11;
    Sst[ln * 4 + 2][jrow] = acc20;  Sst[ln * 4 + 2][jrow + 1] = acc21;
    Sst[ln * 4 + 3][jrow] = acc30;  Sst[ln * 4 + 3][jrow + 1] = acc31;
    __syncthreads();
    const int i_l = t >> 2, jc = (t & 3) * 8;
    float* dst = sc + ((size_t)bb << 18) + (size_t)(i0 + i_l) * 512 + j0 + jc;
    *(float4*)dst       = *(const float4*)&Sst[i_l][jc];
    *(float4*)(dst + 4) = *(const float4*)&Sst[i_l][jc + 4];
}

// ---------------------------------------------------------------------------
// Kernel C: fused softmax + PV + out-proj + residual + LayerNorm.
//   512 blocks x 256 threads; block u: b = u>>7, 4-row tile m0 = (u&127)*4.
//   2 blocks/CU for overlap; MFMA M=16 runs with rows 4..15 zeroed.
// ---------------------------------------------------------------------------
__global__ __launch_bounds__(256) void smpvout_k(
    const float* __restrict__ sc, const ushort* __restrict__ vals_t,
    const ushort* __restrict__ Wot, const float* __restrict__ x,
    const float* __restrict__ bo, const float* __restrict__ gamma,
    const float* __restrict__ beta, float* __restrict__ out)
{
    const int u = blockIdx.x;
    const int b = u >> 7, m0 = (u & 127) * 4;
    const int t = threadIdx.x, w = t >> 6, l = t & 63;
    const int q = l >> 4, ln = l & 15;

    __shared__ __align__(16) ushort attnS[16][520];   // +8 pad
    __shared__ __align__(16) ushort msgS[16][264];    // +8 pad
    __shared__ float redS[4][4], redQ[4][4];

    // zero attnS rows 4..15 (4 waves x 3 rows each, 8 ushorts/lane)
#pragma unroll
    for (int p = 0; p < 3; ++p)
        *(uint4*)&attnS[4 + w + p * 4][l * 8] = make_uint4(0, 0, 0, 0);

    // ---- softmax: 4 rows, one per wave ----
    {
        const int i = m0 + w;
        const float* srow = sc + ((size_t)b << 18) + (size_t)i * S;
        const int j0 = l * 8;
        float v[8];
        *(float4*)&v[0] = *(const float4*)(srow + j0);
        *(float4*)&v[4] = *(const float4*)(srow + j0 + 4);
        float mx = -3.0e38f;
#pragma unroll
        for (int k = 0; k < 8; ++k) {
            v[k] = (j0 + k < i) ? v[k] : -3.0e38f;  // mask before ANY use
            mx = fmaxf(mx, v[k]);
        }
#pragma unroll
        for (int off = 32; off; off >>= 1) mx = fmaxf(mx, __shfl_xor(mx, off, 64));
        float e[8];
        float sum = 0.f;
#pragma unroll
        for (int k = 0; k < 8; ++k) {
            e[k] = __expf(v[k] - mx);
            sum += (j0 + k < i) ? e[k] : 0.f;
        }
#pragma unroll
        for (int off = 32; off; off >>= 1) sum += __shfl_xor(sum, off, 64);
        const float inv = (i > 0) ? (1.f / sum) : 0.f;   // row 0: all-zero
        ushort o[8];
#pragma unroll
        for (int k = 0; k < 8; ++k)
            o[k] = (j0 + k < i) ? f2bf(e[k] * inv) : (ushort)0;
        *(ushort4*)&attnS[w][j0]     = make_ushort4(o[0], o[1], o[2], o[3]);
        *(ushort4*)&attnS[w][j0 + 4] = make_ushort4(o[4], o[5], o[6], o[7]);
    }
    __syncthreads();

    // ---- PV: wave w -> cols w*64 .. w*64+63 (nt 0..3) ----
    const ushort* V = vals_t + (size_t)b * 256 * 512;
    f32x4 acc[4] = {};
    const int kmax = (m0 + 4 + 31) & ~31;   // covers j <= m0+2
    for (int k0 = 0; k0 < kmax; k0 += 32) {
        bf16x8 a = *(const bf16x8*)&attnS[ln][k0 + q * 8];
#pragma unroll
        for (int nt = 0; nt < 4; ++nt) {
            bf16x8 bb = *(const bf16x8*)(V + (size_t)(w * 64 + nt * 16 + ln) * 512 + k0 + q * 8);
            acc[nt] = __builtin_amdgcn_mfma_f32_16x16x32_bf16(a, bb, acc[nt], 0, 0, 0);
        }
    }
#pragma unroll
    for (int nt = 0; nt < 4; ++nt)
#pragma unroll
        for (int r = 0; r < 4; ++r)
            msgS[q * 4 + r][w * 64 + nt * 16 + ln] = f2bf(acc[nt][r]);
    __syncthreads();

    // ---- OUT: wave w -> cols w*64 .. w*64+63; rows 0..3 valid ----
    f32x4 acc2[4] = {};
    for (int k0 = 0; k0 < 256; k0 += 32) {
        bf16x8 a = *(const bf16x8*)&msgS[ln][k0 + q * 8];
#pragma unroll
        for (int nt = 0; nt < 4; ++nt) {
            bf16x8 bb = *(const bf16x8*)(Wot + (size_t)(w * 64 + nt * 16 + ln) * 256 + k0 + q * 8);
            acc2[nt] = __builtin_amdgcn_mfma_f32_16x16x32_bf16(a, bb, acc2[nt], 0, 0, 0);
        }
    }

    const int r0 = (b << 9) + m0;
    float sum[4] = {}, sq[4] = {};
    if (q == 0) {
#pragma unroll
        for (int nt = 0; nt < 4; ++nt) {
            const int col = w * 64 + nt * 16 + ln;
            const float bov = bo[col];
#pragma unroll
            for (int r = 0; r < 4; ++r) {
                const int row = r0 + r;
                float v = acc2[nt][r] + x[(size_t)row * 256 + col] + bov;
                acc2[nt][r] = v;
                sum[r] += v;
                sq[r] += v * v;
            }
        }
    }
#pragma unroll
    for (int r = 0; r < 4; ++r) {
#pragma unroll
        for (int off = 1; off < 16; off <<= 1) {
            sum[r] += __shfl_xor(sum[r], off, 64);
            sq[r]  += __shfl_xor(sq[r],  off, 64);
        }
    }
    if (ln == 0 && q == 0) {
#pragma unroll
        for (int r = 0; r < 4; ++r) {
            redS[r][w] = sum[r];
            redQ[r][w] = sq[r];
        }
    }
    __syncthreads();
    if (q == 0) {
#pragma unroll
        for (int nt = 0; nt < 4; ++nt) {
            const int col = w * 64 + nt * 16 + ln;
            const float g = gamma[col], be = beta[col];
#pragma unroll
            for (int r = 0; r < 4; ++r) {
                const float ts = redS[r][0] + redS[r][1] + redS[r][2] + redS[r][3];
                const float tq = redQ[r][0] + redQ[r][1] + redQ[r][2] + redQ[r][3];
                const float mu = ts * (1.f / 256.f);
                const float var = tq * (1.f / 256.f) - mu * mu;
                out[(size_t)(r0 + r) * 256 + col] =
                    (acc2[nt][r] - mu) * rsqrtf(var + 1e-5f) * g + be;
            }
        }
    }
}

// ---------------------------------------------------------------------------
extern "C" void kernel_launch(void* const* d_in, const int* in_sizes, int n_in,
                              void* d_out, int out_size, void* d_ws, size_t ws_size,
                              hipStream_t stream)
{
    (void)in_sizes; (void)n_in; (void)out_size; (void)ws_size;
    const float* x     = (const float*)d_in[0];
    const float* W1    = (const float*)d_in[1];
    const float* b1    = (const float*)d_in[2];
    const float* w2    = (const float*)d_in[3];
    const float* Wv    = (const float*)d_in[5];
    const float* bv    = (const float*)d_in[6];
    const float* Wo    = (const float*)d_in[7];
    const float* bo    = (const float*)d_in[8];
    const float* gamma = (const float*)d_in[9];
    const float* beta  = (const float*)d_in[10];
    float* out = (float*)d_out;

    // workspace layout in 256KB (64K-float) chunks
    float* ws = (float*)d_ws;
    uint*   hi_p   = (uint*)ws;                        // chunks 0-3   [128 hp][2048] uint
    ushort* hj     = (ushort*)(ws + 4 * (size_t)CH);   // chunks 4-7   [2048][256] f16
    float*  sc     = ws + 8 * (size_t)CH;              // chunks 8-23  (4*512*512 f32)
    ushort* Wot    = (ushort*)(ws + 24 * (size_t)CH);  // chunk 24
    ushort* vals_t = (ushort*)(ws + 25 * (size_t)CH);  // chunks 25-28 ([b][e][j] bf16)

    qkv_pack_k<<<dim3(400),      256, 0, stream>>>(x, W1, Wv, Wo, b1, bv, hi_p, hj, vals_t, Wot);
    scores_k  <<<dim3(16, 8, 4), 256, 0, stream>>>(hi_p, hj, w2, sc);
    smpvout_k <<<dim3(512),      256, 0, stream>>>(sc, vals_t, Wot, x, bo, gamma, beta, out);
}

// Round 8
// 123.514 us; speedup vs baseline: 1.3204x; 1.0907x over previous
//
#include <hip/hip_runtime.h>
#include <math.h>

#define D 256
#define S 512
#define M 2048  // 4 * 512
#define CH (64 * 1024)  // 256KB workspace chunk in floats
#define LTW 76  // lt row width (ushorts), padded

typedef __attribute__((ext_vector_type(8))) short bf16x8;
typedef __attribute__((ext_vector_type(4))) float f32x4;
typedef _Float16 half2v __attribute__((ext_vector_type(2)));

__device__ inline ushort f2bf(float f) {
    union { float f; unsigned u; } v; v.f = f;
    unsigned r = v.u + 0x7FFFu + ((v.u >> 16) & 1u);   // RNE
    return (ushort)(r >> 16);
}

__device__ inline ushort f2h(float f) {
    union { _Float16 h; ushort u; } v; v.h = (_Float16)f; return v.u;
}

__device__ inline uint pack2h(float a, float b) {
    union { half2v h; uint u; } v; v.h[0] = (_Float16)a; v.h[1] = (_Float16)b;
    return v.u;
}

__device__ inline uint pack2u(ushort a, ushort b) {
    return (uint)a | ((uint)b << 16);
}

// relu(a + b) on packed f16 pairs (bit patterns in uint)
__device__ inline uint addrelu2(uint a, uint b) {
    union { uint u; half2v h; } x, y;
    x.u = a; y.u = b;
    half2v s = x.h + y.h;                  // v_pk_add_f16
    half2v z = {};
    s = __builtin_elementwise_max(s, z);   // v_pk_max_f16
    union { half2v h; uint u; } r; r.h = s; return r.u;
}

// acc += dot2(a, b) — f32 accumulate (v_dot2_f32_f16)
__device__ inline float fdot2u(uint a, uint b, float acc) {
    union { uint u; half2v h; } x, y;
    x.u = a; y.u = b;
    return __builtin_amdgcn_fdot2(x.h, y.h, acc, false);
}

// ---------------------------------------------------------------------------
// Kernel A: fused weight-pack + QKV MFMA GEMM.
//   Blocks 0..383: gemm unit (bn = u%12 -> 64-col tile of {WA|WB|Wv}, bm = u/12
//   -> 64-row tile of x).  Packs its own B-tile (bf16 [col][k]) into LDS, runs
//   K-loop.  Outputs:
//     region 0 -> hi_p  [hp][row] uint: packed f16 pair {h=2hp, 2hp+1} (+b1)
//     region 1 -> hj    [row][h]  f16 row-major (coalesced via LDS stage)
//     region 2 -> vals_t [b][e][j] bf16 transposed
//   Blocks 384..399: pack Wot (Wo^T bf16) for kernel C.
// ---------------------------------------------------------------------------
__global__ __launch_bounds__(256) void qkv_pack_k(
    const float* __restrict__ x, const float* __restrict__ W1,
    const float* __restrict__ Wv, const float* __restrict__ Wo,
    const float* __restrict__ b1, const float* __restrict__ bv,
    uint* __restrict__ hi_p, ushort* __restrict__ hj,
    ushort* __restrict__ vals_t, ushort* __restrict__ Wot)
{
    __shared__ union {
        ushort Bs[64][264];   // packed B-tile [col_local][k], +8 pad
        ushort lt[64][LTW];   // transpose staging
    } sh;

    const int u = blockIdx.x;
    const int t = threadIdx.x;

    if (u >= 384) {
        // ---- Wot pack unit (16 blocks): Wot[n][k] = bf16(Wo[k][n]) ----
        const int unit = u - 384;
        const int a0 = (unit >> 2) * 64;   // dst row block (n = src col)
        const int b0 = (unit & 3) * 64;    // dst col block (k = src row)
        const int r = t >> 4;
        const int c = (t & 15) * 4;
#pragma unroll
        for (int p = 0; p < 4; ++p) {
            const int sr = b0 + p * 16 + r;
            float4 v = *(const float4*)(Wo + (size_t)sr * 256 + a0 + c);
            sh.lt[p * 16 + r][c + 0] = f2bf(v.x);
            sh.lt[p * 16 + r][c + 1] = f2bf(v.y);
            sh.lt[p * 16 + r][c + 2] = f2bf(v.z);
            sh.lt[p * 16 + r][c + 3] = f2bf(v.w);
        }
        __syncthreads();
#pragma unroll
        for (int p = 0; p < 4; ++p) {
            const int dr = p * 16 + r;
            ushort4 o = make_ushort4(sh.lt[c + 0][dr], sh.lt[c + 1][dr],
                                     sh.lt[c + 2][dr], sh.lt[c + 3][dr]);
            *(ushort4*)(Wot + (size_t)(a0 + dr) * 256 + b0 + c) = o;
        }
        return;
    }

    // ---- QKV gemm unit ----
    const int bn = u % 12, bm = u / 12;
    const int n0 = bn * 64, m0 = bm * 64;
    const int region = n0 >> 8, c0 = n0 & 255;

    // pack B-tile into LDS: Bs[cl][k] = bf16(Wsrc[k][c0+cl])
    {
        const int cl4 = (t & 15) * 4;
        const int kb = (t >> 4) * 16;
#pragma unroll
        for (int kk = 0; kk < 16; ++kk) {
            const int k = kb + kk;
            float4 v;
            if (region == 0) {
                float4 wa = *(const float4*)(W1 + (size_t)k * 256 + c0 + cl4);
                float4 wc = *(const float4*)(W1 + (size_t)(512 + k) * 256 + c0 + cl4);
                v = make_float4(wa.x + wc.x, wa.y + wc.y, wa.z + wc.z, wa.w + wc.w);
            } else if (region == 1) {
                float4 wb = *(const float4*)(W1 + (size_t)(256 + k) * 256 + c0 + cl4);
                float4 wc = *(const float4*)(W1 + (size_t)(512 + k) * 256 + c0 + cl4);
                v = make_float4(wb.x - wc.x, wb.y - wc.y, wb.z - wc.z, wb.w - wc.w);
            } else {
                v = *(const float4*)(Wv + (size_t)k * 256 + c0 + cl4);
            }
            sh.Bs[cl4 + 0][k] = f2bf(v.x);
            sh.Bs[cl4 + 1][k] = f2bf(v.y);
            sh.Bs[cl4 + 2][k] = f2bf(v.z);
            sh.Bs[cl4 + 3][k] = f2bf(v.w);
        }
    }
    __syncthreads();

    const int w = t >> 6, l = t & 63;
    const int q = l >> 4, ln = l & 15;
    const int wm = (w >> 1) * 32, wn = (w & 1) * 32;

    f32x4 acc[2][2] = {};
    for (int k0 = 0; k0 < 256; k0 += 32) {
        union { bf16x8 v; ushort s[8]; } a[2];
        bf16x8 b[2];
#pragma unroll
        for (int mt = 0; mt < 2; ++mt) {
            const float* xr = x + (size_t)(m0 + wm + mt * 16 + ln) * 256 + k0 + q * 8;
            float4 u0 = *(const float4*)xr;
            float4 u1 = *(const float4*)(xr + 4);
            a[mt].s[0] = f2bf(u0.x); a[mt].s[1] = f2bf(u0.y);
            a[mt].s[2] = f2bf(u0.z); a[mt].s[3] = f2bf(u0.w);
            a[mt].s[4] = f2bf(u1.x); a[mt].s[5] = f2bf(u1.y);
            a[mt].s[6] = f2bf(u1.z); a[mt].s[7] = f2bf(u1.w);
        }
#pragma unroll
        for (int nt = 0; nt < 2; ++nt)
            b[nt] = *(const bf16x8*)&sh.Bs[wn + nt * 16 + ln][k0 + q * 8];
#pragma unroll
        for (int mt = 0; mt < 2; ++mt)
#pragma unroll
            for (int nt = 0; nt < 2; ++nt)
                acc[mt][nt] = __builtin_amdgcn_mfma_f32_16x16x32_bf16(a[mt].v, b[nt], acc[mt][nt], 0, 0, 0);
    }

    __syncthreads();   // all Bs reads done before aliasing as lt

    if (region == 0) {
        // stage f16(acc + b1) into lt[col_local][row_local]
#pragma unroll
        for (int nt = 0; nt < 2; ++nt) {
            const int cl = wn + nt * 16 + ln;
            const float bias = b1[c0 + cl];
#pragma unroll
            for (int mt = 0; mt < 2; ++mt)
#pragma unroll
                for (int r = 0; r < 4; ++r)
                    sh.lt[cl][wm + mt * 16 + q * 4 + r] = f2h(acc[mt][nt][r] + bias);
        }
        __syncthreads();
        // readout: hi_p[(c0>>1)+hpl][m0+r4 .. +3], pair-packed, 16B coalesced
#pragma unroll
        for (int p = 0; p < 2; ++p) {
            const int qid = p * 256 + t;
            const int r4 = (qid & 15) * 4;
            const int hpl = qid >> 4;          // 0..31
            uint4 o;
            o.x = pack2u(sh.lt[2 * hpl][r4 + 0], sh.lt[2 * hpl + 1][r4 + 0]);
            o.y = pack2u(sh.lt[2 * hpl][r4 + 1], sh.lt[2 * hpl + 1][r4 + 1]);
            o.z = pack2u(sh.lt[2 * hpl][r4 + 2], sh.lt[2 * hpl + 1][r4 + 2]);
            o.w = pack2u(sh.lt[2 * hpl][r4 + 3], sh.lt[2 * hpl + 1][r4 + 3]);
            *(uint4*)(hi_p + (size_t)((c0 >> 1) + hpl) * 2048 + m0 + r4) = o;
        }
    } else if (region == 1) {
        // stage f16(acc) into lt[col_local][row_local]
#pragma unroll
        for (int nt = 0; nt < 2; ++nt) {
            const int cl = wn + nt * 16 + ln;
#pragma unroll
            for (int mt = 0; mt < 2; ++mt)
#pragma unroll
                for (int r = 0; r < 4; ++r)
                    sh.lt[cl][wm + mt * 16 + q * 4 + r] = f2h(acc[mt][nt][r]);
        }
        __syncthreads();
        // readout row-major: hj[m0+rl][c0+cg*8 ..], 16B coalesced
#pragma unroll
        for (int p = 0; p < 2; ++p) {
            const int qid = p * 256 + t;
            const int cg = qid & 7;
            const int rl = qid >> 3;           // 0..63
            ushort o[8];
#pragma unroll
            for (int k = 0; k < 8; ++k) o[k] = sh.lt[cg * 8 + k][rl];
            *(uint4*)(hj + (size_t)(m0 + rl) * 256 + c0 + cg * 8) = *(const uint4*)o;
        }
    } else {
        // stage bias-added bf16 into lt[col_local][row_local], store transposed
#pragma unroll
        for (int nt = 0; nt < 2; ++nt) {
            const int cl = wn + nt * 16 + ln;
            const float bias = bv[c0 + cl];
#pragma unroll
            for (int mt = 0; mt < 2; ++mt)
#pragma unroll
                for (int r = 0; r < 4; ++r)
                    sh.lt[cl][wm + mt * 16 + q * 4 + r] = f2bf(acc[mt][nt][r] + bias);
        }
        __syncthreads();
        const int bb = m0 >> 9, jloc = m0 & 511;
#pragma unroll
        for (int p = 0; p < 2; ++p) {
            const int idx = p * 256 + t;
            const int e_l = idx & 63, jc = (idx >> 6) * 8;
            *(uint4*)(vals_t + ((size_t)(bb * 256 + c0 + e_l)) * 512 + jloc + jc) =
                *(const uint4*)&sh.lt[e_l][jc];
        }
    }
}

// ---------------------------------------------------------------------------
// Kernel B: scores, 64i x 32j tiles, packed-f16 dot2 inner loop.
//   Full hi_p block-tile (128 hp x 64 i = 32KB) staged to LDS upfront with
//   coalesced uint4 copies + ONE sync; main loop is LDS reads + hj L2 loads
//   + dot2 VALU with ZERO barriers (freely software-pipelined).
// ---------------------------------------------------------------------------
__global__ __launch_bounds__(256) void scores_k(
    const uint* __restrict__ hi_p, const ushort* __restrict__ hj,
    const float* __restrict__ w2, float* __restrict__ sc)
{
    const int jt = blockIdx.x, it = blockIdx.y, bb = blockIdx.z;
    if (jt > 2 * it + 1) return;
    const int i0 = it * 64, j0 = jt * 32;
    const int t = threadIdx.x, w = t >> 6, l = t & 63;
    const int q = l >> 4, ln = l & 15;

    __shared__ __align__(16) uint Hi[128][64];     // [hp][i_local] packed half2
    __shared__ __align__(16) float Sst[64][36];    // output staging
    __shared__ uint w2u[128];                      // w2 packed half2

    if (t < 64) {
        float4 wv = *(const float4*)(w2 + t * 4);
        w2u[t * 2 + 0] = pack2h(wv.x, wv.y);
        w2u[t * 2 + 1] = pack2h(wv.z, wv.w);
    }
    // stage hi_p tile: 128 hp x 64 i, 8 uint4 per thread, coalesced
    {
        const int gbase = (bb << 9) + i0;
#pragma unroll
        for (int p = 0; p < 8; ++p) {
            const int idx = p * 256 + t;
            const int hp = idx >> 4;
            const int il = (idx & 15) * 4;
            *(uint4*)&Hi[hp][il] =
                *(const uint4*)(hi_p + (size_t)hp * 2048 + gbase + il);
        }
    }
    __syncthreads();

    const int jrow = w * 8 + q * 2;
    const ushort* hj0 = hj + (size_t)((bb << 9) + j0 + jrow) * 256;
    const ushort* hj1 = hj0 + 256;
    const int i4 = ln * 4;

    float acc00 = 0.f, acc01 = 0.f, acc10 = 0.f, acc11 = 0.f;
    float acc20 = 0.f, acc21 = 0.f, acc30 = 0.f, acc31 = 0.f;

    for (int hc = 0; hc < 256; hc += 32) {
        const int hp0 = hc >> 1;
        uint e0u[16], e1u[16];
#pragma unroll
        for (int c = 0; c < 4; ++c) {
            *(uint4*)&e0u[c * 4] = *(const uint4*)(hj0 + hc + c * 8);
            *(uint4*)&e1u[c * 4] = *(const uint4*)(hj1 + hc + c * 8);
        }
#pragma unroll
        for (int hp = 0; hp < 16; ++hp) {
            uint4 av = *(const uint4*)&Hi[hp0 + hp][i4];
            const uint wv = w2u[hp0 + hp];
            const uint f0 = e0u[hp], f1 = e1u[hp];
            acc00 = fdot2u(addrelu2(av.x, f0), wv, acc00);
            acc01 = fdot2u(addrelu2(av.x, f1), wv, acc01);
            acc10 = fdot2u(addrelu2(av.y, f0), wv, acc10);
            acc11 = fdot2u(addrelu2(av.y, f1), wv, acc11);
            acc20 = fdot2u(addrelu2(av.z, f0), wv, acc20);
            acc21 = fdot2u(addrelu2(av.z, f1), wv, acc21);
            acc30 = fdot2u(addrelu2(av.w, f0), wv, acc30);
            acc31 = fdot2u(addrelu2(av.w, f1), wv, acc31);
        }
    }

    Sst[ln * 4 + 0][jrow] = acc00;  Sst[ln * 4 + 0][jrow + 1] = acc01;
    Sst[ln * 4 + 1][jrow] = acc10;  Sst[ln * 4 + 1][jrow + 1] = acc11;
    Sst[ln * 4 + 2][jrow] = acc20;  Sst[ln * 4 + 2][jrow + 1] = acc21;
    Sst[ln * 4 + 3][jrow] = acc30;  Sst[ln * 4 + 3][jrow + 1] = acc31;
    __syncthreads();
    const int i_l = t >> 2, jc = (t & 3) * 8;
    float* dst = sc + ((size_t)bb << 18) + (size_t)(i0 + i_l) * 512 + j0 + jc;
    *(float4*)dst       = *(const float4*)&Sst[i_l][jc];
    *(float4*)(dst + 4) = *(const float4*)&Sst[i_l][jc + 4];
}

// ---------------------------------------------------------------------------
// Kernel C: fused softmax + PV + out-proj + residual + LayerNorm.
//   256 blocks x 512 threads; block u: b = u>>6, 8-row tile m0 = (u&63)*8.
//   All CUs active, 2 waves/SIMD.  (Measured-good r5 variant.)
// ---------------------------------------------------------------------------
__global__ __launch_bounds__(512) void smpvout_k(
    const float* __restrict__ sc, const ushort* __restrict__ vals_t,
    const ushort* __restrict__ Wot, const float* __restrict__ x,
    const float* __restrict__ bo, const float* __restrict__ gamma,
    const float* __restrict__ beta, float* __restrict__ out)
{
    const int u = blockIdx.x;
    const int b = u >> 6, m0 = (u & 63) * 8;
    const int t = threadIdx.x, w = t >> 6, l = t & 63;
    const int q = l >> 4, ln = l & 15;

    __shared__ __align__(16) ushort attnS[16][520];   // +8 pad
    __shared__ __align__(16) ushort msgS[16][264];    // +8 pad
    __shared__ float redS[8][8], redQ[8][8];

    // zero attnS rows 8..15 (512 threads x 8 ushorts)
    *(uint4*)&attnS[8 + (t >> 6)][(t & 63) * 8] = make_uint4(0, 0, 0, 0);

    // ---- softmax: 8 rows, one per wave ----
    {
        const int i = m0 + w;
        const float* srow = sc + ((size_t)b << 18) + (size_t)i * S;
        const int j0 = l * 8;
        float v[8];
        *(float4*)&v[0] = *(const float4*)(srow + j0);
        *(float4*)&v[4] = *(const float4*)(srow + j0 + 4);
        float mx = -3.0e38f;
#pragma unroll
        for (int k = 0; k < 8; ++k) {
            v[k] = (j0 + k < i) ? v[k] : -3.0e38f;  // mask before ANY use
            mx = fmaxf(mx, v[k]);
        }
#pragma unroll
        for (int off = 32; off; off >>= 1) mx = fmaxf(mx, __shfl_xor(mx, off, 64));
        float e[8];
        float sum = 0.f;
#pragma unroll
        for (int k = 0; k < 8; ++k) {
            e[k] = __expf(v[k] - mx);
            sum += (j0 + k < i) ? e[k] : 0.f;
        }
#pragma unroll
        for (int off = 32; off; off >>= 1) sum += __shfl_xor(sum, off, 64);
        const float inv = (i > 0) ? (1.f / sum) : 0.f;   // row 0: all-zero
        ushort o[8];
#pragma unroll
        for (int k = 0; k < 8; ++k)
            o[k] = (j0 + k < i) ? f2bf(e[k] * inv) : (ushort)0;
        *(ushort4*)&attnS[w][j0]     = make_ushort4(o[0], o[1], o[2], o[3]);
        *(ushort4*)&attnS[w][j0 + 4] = make_ushort4(o[4], o[5], o[6], o[7]);
    }
    __syncthreads();

    // ---- PV: wave w -> cols w*32..w*32+31 (nt 0..1) ----
    const ushort* V = vals_t + (size_t)b * 256 * 512;
    f32x4 acc[2] = {};
    const int kmax = (m0 + 8 + 31) & ~31;   // covers j <= m0+6
    for (int k0 = 0; k0 < kmax; k0 += 32) {
        bf16x8 a = *(const bf16x8*)&attnS[ln][k0 + q * 8];
#pragma unroll
        for (int nt = 0; nt < 2; ++nt) {
            bf16x8 bb = *(const bf16x8*)(V + (size_t)(w * 32 + nt * 16 + ln) * 512 + k0 + q * 8);
            acc[nt] = __builtin_amdgcn_mfma_f32_16x16x32_bf16(a, bb, acc[nt], 0, 0, 0);
        }
    }
#pragma unroll
    for (int nt = 0; nt < 2; ++nt)
#pragma unroll
        for (int r = 0; r < 4; ++r)
            msgS[q * 4 + r][w * 32 + nt * 16 + ln] = f2bf(acc[nt][r]);
    __syncthreads();

    // ---- OUT: wave w -> cols w*32..w*32+31; rows 0..7 valid ----
    f32x4 acc2[2] = {};
    for (int k0 = 0; k0 < 256; k0 += 32) {
        bf16x8 a = *(const bf16x8*)&msgS[ln][k0 + q * 8];
#pragma unroll
        for (int nt = 0; nt < 2; ++nt) {
            bf16x8 bb = *(const bf16x8*)(Wot + (size_t)(w * 32 + nt * 16 + ln) * 256 + k0 + q * 8);
            acc2[nt] = __builtin_amdgcn_mfma_f32_16x16x32_bf16(a, bb, acc2[nt], 0, 0, 0);
        }
    }

    const int r0 = (b << 9) + m0;
    float sum[4] = {}, sq[4] = {};
    if (q < 2) {
#pragma unroll
        for (int nt = 0; nt < 2; ++nt) {
            const int col = w * 32 + nt * 16 + ln;
            const float bov = bo[col];
#pragma unroll
            for (int r = 0; r < 4; ++r) {
                const int row = r0 + q * 4 + r;
                float v = acc2[nt][r] + x[(size_t)row * 256 + col] + bov;
                acc2[nt][r] = v;
                sum[r] += v;
                sq[r] += v * v;
            }
        }
    }
#pragma unroll
    for (int r = 0; r < 4; ++r) {
#pragma unroll
        for (int off = 1; off < 16; off <<= 1) {
            sum[r] += __shfl_xor(sum[r], off, 64);
            sq[r]  += __shfl_xor(sq[r],  off, 64);
        }
    }
    if (ln == 0 && q < 2) {
#pragma unroll
        for (int r = 0; r < 4; ++r) {
            redS[q * 4 + r][w] = sum[r];
            redQ[q * 4 + r][w] = sq[r];
        }
    }
    __syncthreads();
    if (q < 2) {
#pragma unroll
        for (int nt = 0; nt < 2; ++nt) {
            const int col = w * 32 + nt * 16 + ln;
            const float g = gamma[col], be = beta[col];
#pragma unroll
            for (int r = 0; r < 4; ++r) {
                const int rl = q * 4 + r;
                float ts = 0.f, tq = 0.f;
#pragma unroll
                for (int k = 0; k < 8; ++k) { ts += redS[rl][k]; tq += redQ[rl][k]; }
                const float mu = ts * (1.f / 256.f);
                const float var = tq * (1.f / 256.f) - mu * mu;
                out[(size_t)(r0 + rl) * 256 + col] =
                    (acc2[nt][r] - mu) * rsqrtf(var + 1e-5f) * g + be;
            }
        }
    }
}

// ---------------------------------------------------------------------------
extern "C" void kernel_launch(void* const* d_in, const int* in_sizes, int n_in,
                              void* d_out, int out_size, void* d_ws, size_t ws_size,
                              hipStream_t stream)
{
    (void)in_sizes; (void)n_in; (void)out_size; (void)ws_size;
    const float* x     = (const float*)d_in[0];
    const float* W1    = (const float*)d_in[1];
    const float* b1    = (const float*)d_in[2];
    const float* w2    = (const float*)d_in[3];
    const float* Wv    = (const float*)d_in[5];
    const float* bv    = (const float*)d_in[6];
    const float* Wo    = (const float*)d_in[7];
    const float* bo    = (const float*)d_in[8];
    const float* gamma = (const float*)d_in[9];
    const float* beta  = (const float*)d_in[10];
    float* out = (float*)d_out;

    // workspace layout in 256KB (64K-float) chunks
    float* ws = (float*)d_ws;
    uint*   hi_p   = (uint*)ws;                        // chunks 0-3   [128 hp][2048] uint
    ushort* hj     = (ushort*)(ws + 4 * (size_t)CH);   // chunks 4-7   [2048][256] f16
    float*  sc     = ws + 8 * (size_t)CH;              // chunks 8-23  (4*512*512 f32)
    ushort* Wot    = (ushort*)(ws + 24 * (size_t)CH);  // chunk 24
    ushort* vals_t = (ushort*)(ws + 25 * (size_t)CH);  // chunks 25-28 ([b][e][j] bf16)

    qkv_pack_k<<<dim3(400),      256, 0, stream>>>(x, W1, Wv, Wo, b1, bv, hi_p, hj, vals_t, Wot);
    scores_k  <<<dim3(16, 8, 4), 256, 0, stream>>>(hi_p, hj, w2, sc);
    smpvout_k <<<dim3(256),      512, 0, stream>>>(sc, vals_t, Wot, x, bo, gamma, beta, out);
}